// Round 6
// baseline (810.464 us; speedup 1.0000x reference)
//
#include <hip/hip_runtime.h>
#include <math.h>

typedef __bf16 bf16_t;
typedef bf16_t bf16x4 __attribute__((ext_vector_type(4)));
typedef bf16_t bf16x8 __attribute__((ext_vector_type(8)));
typedef float  f32x16 __attribute__((ext_vector_type(16)));

#define HH 1024
#define CC 8
#define DD 64
#define FF 32
#define WW 7
#define HP 1018
#define HPAD 1024
#define NF 128
#define QOUT (NF*HP*DD)
#define QWS ((size_t)NF*HPAD*DD)

#if __has_builtin(__builtin_amdgcn_exp2f)
#define EXP2(x) __builtin_amdgcn_exp2f(x)
#else
#define EXP2(x) __expf((x) * 0.6931471805599453f)
#endif

// q1 is pre-scaled by log2(e)/1018 at conv time, so flash computes exp2(S) directly.
#define QSCALE (1.442695040888963f / 1018.f)

// Vt: row stride 64 bf16, XOR-swizzled 8-element chunks (validated R4):
//   addr(row, col) = row*64 + (((col>>3) ^ (row&7) ^ ((row>>2)&7))<<3) + (col&7)
__device__ __forceinline__ int vaddr(int row, int col) {
    return row*64 + ((((col>>3) ^ (row&7) ^ ((row>>2)&7)))<<3) + (col&7);
}

// ---------------- W transpose: Wt[f][c][d][j] -> Wp[f][c][j][d] ----------------
__global__ __launch_bounds__(256) void wprep_kernel(
    const float* __restrict__ Wt, float* __restrict__ Wp)
{
    const int idx = blockIdx.x * 256 + threadIdx.x;
    if (idx < FF*CC*DD*WW) {
        const int j = idx % WW;
        int t = idx / WW;
        const int d = t % DD; t /= DD;
        const int c = t % CC;
        const int f = t / CC;
        Wp[((f*CC + c)*WW + j)*DD + d] = Wt[idx];
    }
}

// ---------------- projection (grouped conv) ----------------
// 16-row h-tiles: staged window 22 rows = 45 KB LDS -> 3 blocks/CU.
// xs identity copy [row][c][d]; compute reads xs[row*512 + c*64 + d]: lanes differ
// only in d -> 2 lanes/bank, conflict-free.
// grid (64, 4, 8): z&1 selects input, z>>1 selects filter pair (2 f/thread).
__global__ __launch_bounds__(256, 3) void conv_kernel(
    const float* __restrict__ x1, const float* __restrict__ x2,
    const float* __restrict__ Wp, bf16_t* __restrict__ q1, bf16_t* __restrict__ q2)
{
    __shared__ float xs[22*512];
    const int zin = blockIdx.z & 1;
    const int fh = blockIdx.z >> 1;       // 0..3
    const float* x = zin ? x2 : x1;
    bf16_t* q = zin ? q2 : q1;
    const float qs = zin ? 1.f : QSCALE;  // bake softmax scale into q1
    const int n = blockIdx.y;
    const int hb = blockIdx.x * 16;
    const int tid = threadIdx.x;

    const float4* xg = (const float4*)(x + (size_t)n*HH*512);
    float4* xsv = (float4*)xs;
#pragma unroll
    for (int it = 0; it < 11; ++it) {     // 22*128 / 256 = 11
        const int i = it*256 + tid;
        const int row = hb + (i >> 7);
        float4 v = {0.f, 0.f, 0.f, 0.f};
        if (row < HH) v = xg[(size_t)row*128 + (i & 127)];
        xsv[i] = v;
    }

    const int d = tid & 63;
    const int fq = tid >> 6;

    // weights for this thread's 2 filters, issued before the barrier
    float w[2][CC][WW];
#pragma unroll
    for (int fi = 0; fi < 2; ++fi) {
        const int f = fq*8 + fh*2 + fi;
#pragma unroll
        for (int c = 0; c < CC; ++c)
#pragma unroll
            for (int j = 0; j < WW; ++j)
                w[fi][c][j] = Wp[((f*CC + c)*WW + j)*DD + d];
    }

    __syncthreads();

    float acc[2][16];
#pragma unroll
    for (int fi = 0; fi < 2; ++fi)
#pragma unroll
        for (int i = 0; i < 16; ++i) acc[fi][i] = 0.f;

#pragma unroll
    for (int rr = 0; rr < 22; ++rr) {
        float xv[CC];
#pragma unroll
        for (int c = 0; c < CC; ++c)
            xv[c] = xs[rr*512 + c*64 + d];
#pragma unroll
        for (int fi = 0; fi < 2; ++fi)
#pragma unroll
            for (int j = 0; j < WW; ++j) {
                const int i = rr - j;          // compile-time guard (full unroll)
                if (i >= 0 && i < 16) {
#pragma unroll
                    for (int c = 0; c < CC; ++c)
                        acc[fi][i] = fmaf(xv[c], w[fi][c][j], acc[fi][i]);
                }
            }
    }

#pragma unroll
    for (int fi = 0; fi < 2; ++fi) {
        const int f = fq*8 + fh*2 + fi;
#pragma unroll
        for (int i = 0; i < 16; ++i) {
            const int h = hb + i;
            const float v = (h < HP) ? acc[fi][i]*qs : 0.f;
            q[((size_t)(n*FF + f)*HPAD + h)*DD + d] = (bf16_t)v;
        }
    }
}

__device__ __forceinline__ float fast_tanh(float x) {
    const float t = __expf(2.f * x);
    return (t - 1.f) / (t + 1.f);
}

// ---------------- fused flash pass (MFMA), 32 h-rows/wave, 8 waves/block ----------
// grid (4, NF) x 512 threads: same 4 blocks/head as before -> FETCH unchanged,
// but waves double: 4096 waves = 4 waves/SIMD (was 2). h split across WAVES
// inside the block, NOT across blocks (R1's mistake: 8 blocks/head duplicated
// the q2/V streams, FETCH 41->76 MB).
// Vt double-buffered, 1 barrier/tile; staged by waves 0-3 only (validated
// 256-thread map); waves 4-7 skip staging -- the co-resident block fills the SIMD.
// Sᵀ = Q2·Q1ᵀ : C/D col=lane&31 -> h on lanes; row=(reg&3)+8*(reg>>2)+4*(lane>>5) -> g.
template<int MODE>
__global__ __launch_bounds__(512, 4) void flash(
    const bf16_t* __restrict__ q1, const bf16_t* __restrict__ q2,
    const bf16_t* __restrict__ vsrc, bf16_t* __restrict__ p1out,
    float* __restrict__ out)
{
    __shared__ __align__(16) bf16_t Vt[2][64*64];  // V^T tiles [d][p(g)], swizzled

    const int head = blockIdx.y;
    const int n = head >> 5, f = head & 31;
    const int tid = threadIdx.x;
    const int w = tid >> 6;                        // 0..7
    const int lane = tid & 63;
    const int lid = lane & 31;
    const int half = lane >> 5;
    const int hb = blockIdx.x * 256 + w * 32;      // 32 h-rows per wave

    const size_t qoff = (size_t)head * HPAD * DD;
    const int vswz = (lid & 7) ^ (lid >> 2);

    // Vt staging map (threads 0..255 only): rows g=4gq..4gq+3, cols 4dq..4dq+3
    const bool stg = (tid < 256);
    const int gq = (tid & 255) >> 4;
    const int dq = tid & 15;
    const int cgb = 4*((gq>>1)&1) + 8*(gq&1) + 16*(gq>>2);   // permuted col base

    const bf16_t* vptr = (MODE == 1) ? vsrc : q2;

    // hoisted per-thread base pointers
    const bf16_t* bp = q1 + qoff + (size_t)(hb + lid)*DD + 8*half;
    const bf16_t* ap = q2 + qoff + (size_t)lid*DD + 8*half;
    const bf16_t* vp = vptr + qoff + (size_t)(4*gq)*DD + 4*dq;

    // Q1 B-fragments, persistent in registers (pre-scaled by QSCALE in conv)
    bf16x8 bq1[4];
#pragma unroll
    for (int kt = 0; kt < 4; ++kt)
        bq1[kt] = *(const bf16x8*)&bp[16*kt];

    // A-fragments for tile 0 (from global)
    bf16x8 aq[2][4];
#pragma unroll
    for (int mt = 0; mt < 2; ++mt)
#pragma unroll
        for (int kt = 0; kt < 4; ++kt)
            aq[mt][kt] = *(const bf16x8*)&ap[(size_t)(32*mt)*DD + 16*kt];

    // V staging regs: tile 0 -> write buffer 0 now; then prefetch tile 1
    bf16x4 rV[4];
    if (stg) {
#pragma unroll
        for (int i = 0; i < 4; ++i)
            rV[i] = *(const bf16x4*)&vp[(size_t)i*DD];
#pragma unroll
        for (int j = 0; j < 4; ++j) {
            bf16x4 c = { rV[0][j], rV[1][j], rV[2][j], rV[3][j] };
            *(bf16x4*)&Vt[0][vaddr(4*dq + j, cgb)] = c;
        }
#pragma unroll
        for (int i = 0; i < 4; ++i)
            rV[i] = *(const bf16x4*)&vp[(size_t)(64 + i)*DD];
    }

    f32x16 O[2] = {};
    float lacc = 0.f;

    __syncthreads();                               // Vt[0] ready

    for (int t = 0; t < 16; ++t) {
        const int g0 = t << 6;
        const bf16_t* vtc = Vt[t & 1];
        const bool tail = (t == 15);

        // stage NEXT V tile into the inactive buffer (rV holds tile t+1 data),
        // then prefetch rV for tile t+2 -- overlapped with this tile's compute
        if (stg && t + 1 < 16) {
            bf16_t* vtn = Vt[(t + 1) & 1];
#pragma unroll
            for (int j = 0; j < 4; ++j) {
                bf16x4 c = { rV[0][j], rV[1][j], rV[2][j], rV[3][j] };
                *(bf16x4*)&vtn[vaddr(4*dq + j, cgb)] = c;
            }
            if (t + 2 < 16) {
#pragma unroll
                for (int i = 0; i < 4; ++i)
                    rV[i] = *(const bf16x4*)&vp[(size_t)((t + 2)*64 + i)*DD];
            }
        }

#pragma unroll
        for (int mt = 0; mt < 2; ++mt) {
            // ---- S-phase: A-frags from registers (global-prefetched) ----
            f32x16 C = {};
            __builtin_amdgcn_s_setprio(1);
#pragma unroll
            for (int kt = 0; kt < 4; ++kt)
                C = __builtin_amdgcn_mfma_f32_32x32x16_bf16(aq[mt][kt], bq1[kt], C, 0,0,0);
            __builtin_amdgcn_s_setprio(0);
            // reload this mt's A-frags for the NEXT tile (long latency window)
            if (t + 1 < 16) {
#pragma unroll
                for (int kt = 0; kt < 4; ++kt)
                    aq[mt][kt] = *(const bf16x8*)&ap[(size_t)((t + 1)*64 + 32*mt)*DD + 16*kt];
            }
            // ---- exp + pack PV A-frags (no mul: q1 pre-scaled) ----
            bf16x8 af[2];
            float ls = 0.f;
#pragma unroll
            for (int s = 0; s < 16; ++s) {
                float e = EXP2(C[s]);
                if (tail) {
                    const int gg = g0 + 32*mt + (s&3) + 8*(s>>2) + 4*half;
                    if (gg >= HP) e = 0.f;
                }
                ls += e;
                af[s>>3][s&7] = (bf16_t)e;
            }
            lacc += ls;
            // ---- PV: swizzled Vt b128 reads (conflict-free, validated R4) ----
            __builtin_amdgcn_s_setprio(1);
#pragma unroll
            for (int u = 0; u < 2; ++u) {
#pragma unroll
                for (int dt = 0; dt < 2; ++dt) {
                    const int chunk = (4*mt + 2*u + half) ^ vswz;
                    bf16x8 b = *(const bf16x8*)&vtc[(32*dt + lid)*64 + chunk*8];
                    O[dt] = __builtin_amdgcn_mfma_f32_32x32x16_bf16(af[u], b, O[dt], 0,0,0);
                }
            }
            __builtin_amdgcn_s_setprio(0);
        }
        __syncthreads();                           // vtn writes visible; vtc free
    }

    // ---- epilogue ----
    const float l = lacc + __shfl_xor(lacc, 32);
    const float linv = 1.f / l;
#pragma unroll
    for (int s = 0; s < 16; ++s) {
        const int R = (s&3) + 8*(s>>2) + 4*half;
        const float li = __shfl(linv, R);
        const int hg = hb + R;
#pragma unroll
        for (int dt = 0; dt < 2; ++dt) {
            const int d = 32*dt + lid;
            const float val = O[dt][s] * li;
            if (hg < HP)
                out[(((size_t)n*HP + hg)*FF + f)*DD + d] = fast_tanh(val);
            if (MODE == 0)   // zero-pad p1 rows >= HP so pass B stages clean data
                p1out[qoff + (size_t)hg*DD + d] = (bf16_t)(hg < HP ? val : 0.f);
        }
    }
}

extern "C" void kernel_launch(void* const* d_in, const int* in_sizes, int n_in,
                              void* d_out, int out_size, void* d_ws, size_t ws_size,
                              hipStream_t stream)
{
    const float* prot1 = (const float*)d_in[0];
    const float* prot2 = (const float*)d_in[1];
    const float* Wt    = (const float*)d_in[2];
    float* out = (float*)d_out;

    bf16_t* q1b = (bf16_t*)d_ws;
    bf16_t* q2b = q1b + QWS;
    bf16_t* p1b = q2b + QWS;
    float* Wp   = (float*)(p1b + QWS);

    wprep_kernel<<<dim3(448), 256, 0, stream>>>(Wt, Wp);
    conv_kernel<<<dim3(64, 4, 8), 256, 0, stream>>>(prot1, prot2, Wp, q1b, q2b);
    flash<0><<<dim3(4, NF), 512, 0, stream>>>(q1b, q2b, q2b, p1b, out);
    flash<1><<<dim3(4, NF), 512, 0, stream>>>(q1b, q2b, p1b, p1b, out + QOUT);
}

// Round 7
// 720.391 us; speedup vs baseline: 1.1250x; 1.1250x over previous
//
#include <hip/hip_runtime.h>
#include <math.h>

typedef __bf16 bf16_t;
typedef bf16_t bf16x4 __attribute__((ext_vector_type(4)));
typedef bf16_t bf16x8 __attribute__((ext_vector_type(8)));
typedef float  f32x16 __attribute__((ext_vector_type(16)));

#define HH 1024
#define CC 8
#define DD 64
#define FF 32
#define WW 7
#define HP 1018
#define HPAD 1024
#define NF 128
#define QOUT (NF*HP*DD)
#define QWS ((size_t)NF*HPAD*DD)

#if __has_builtin(__builtin_amdgcn_exp2f)
#define EXP2(x) __builtin_amdgcn_exp2f(x)
#else
#define EXP2(x) __expf((x) * 0.6931471805599453f)
#endif

// q1 is pre-scaled by log2(e)/1018 at conv time, so flash computes exp2(S) directly.
#define QSCALE (1.442695040888963f / 1018.f)

// Vt: row stride 64 bf16, XOR-swizzled 8-element chunks (validated R4):
//   addr(row, col) = row*64 + (((col>>3) ^ (row&7) ^ ((row>>2)&7))<<3) + (col&7)
__device__ __forceinline__ int vaddr(int row, int col) {
    return row*64 + ((((col>>3) ^ (row&7) ^ ((row>>2)&7)))<<3) + (col&7);
}

// ---------------- W transpose: Wt[f][c][d][j] -> Wp[f][c][j][d] ----------------
__global__ __launch_bounds__(256) void wprep_kernel(
    const float* __restrict__ Wt, float* __restrict__ Wp)
{
    const int idx = blockIdx.x * 256 + threadIdx.x;
    if (idx < FF*CC*DD*WW) {
        const int j = idx % WW;
        int t = idx / WW;
        const int d = t % DD; t /= DD;
        const int c = t % CC;
        const int f = t / CC;
        Wp[((f*CC + c)*WW + j)*DD + d] = Wt[idx];
    }
}

// ---------------- projection (grouped conv) ----------------
// 16-row h-tiles: staged window 22 rows = 45 KB LDS -> 3 blocks/CU.
// xs identity copy [row][c][d]; compute reads xs[row*512 + c*64 + d]: lanes differ
// only in d -> 2 lanes/bank, conflict-free.
// grid (64, 4, 8): z&1 selects input, z>>1 selects filter pair (2 f/thread).
__global__ __launch_bounds__(256, 3) void conv_kernel(
    const float* __restrict__ x1, const float* __restrict__ x2,
    const float* __restrict__ Wp, bf16_t* __restrict__ q1, bf16_t* __restrict__ q2)
{
    __shared__ float xs[22*512];
    const int zin = blockIdx.z & 1;
    const int fh = blockIdx.z >> 1;       // 0..3
    const float* x = zin ? x2 : x1;
    bf16_t* q = zin ? q2 : q1;
    const float qs = zin ? 1.f : QSCALE;  // bake softmax scale into q1
    const int n = blockIdx.y;
    const int hb = blockIdx.x * 16;
    const int tid = threadIdx.x;

    const float4* xg = (const float4*)(x + (size_t)n*HH*512);
    float4* xsv = (float4*)xs;
#pragma unroll
    for (int it = 0; it < 11; ++it) {     // 22*128 / 256 = 11
        const int i = it*256 + tid;
        const int row = hb + (i >> 7);
        float4 v = {0.f, 0.f, 0.f, 0.f};
        if (row < HH) v = xg[(size_t)row*128 + (i & 127)];
        xsv[i] = v;
    }

    const int d = tid & 63;
    const int fq = tid >> 6;

    // weights for this thread's 2 filters, issued before the barrier
    float w[2][CC][WW];
#pragma unroll
    for (int fi = 0; fi < 2; ++fi) {
        const int f = fq*8 + fh*2 + fi;
#pragma unroll
        for (int c = 0; c < CC; ++c)
#pragma unroll
            for (int j = 0; j < WW; ++j)
                w[fi][c][j] = Wp[((f*CC + c)*WW + j)*DD + d];
    }

    __syncthreads();

    float acc[2][16];
#pragma unroll
    for (int fi = 0; fi < 2; ++fi)
#pragma unroll
        for (int i = 0; i < 16; ++i) acc[fi][i] = 0.f;

#pragma unroll
    for (int rr = 0; rr < 22; ++rr) {
        float xv[CC];
#pragma unroll
        for (int c = 0; c < CC; ++c)
            xv[c] = xs[rr*512 + c*64 + d];
#pragma unroll
        for (int fi = 0; fi < 2; ++fi)
#pragma unroll
            for (int j = 0; j < WW; ++j) {
                const int i = rr - j;          // compile-time guard (full unroll)
                if (i >= 0 && i < 16) {
#pragma unroll
                    for (int c = 0; c < CC; ++c)
                        acc[fi][i] = fmaf(xv[c], w[fi][c][j], acc[fi][i]);
                }
            }
    }

#pragma unroll
    for (int fi = 0; fi < 2; ++fi) {
        const int f = fq*8 + fh*2 + fi;
#pragma unroll
        for (int i = 0; i < 16; ++i) {
            const int h = hb + i;
            const float v = (h < HP) ? acc[fi][i]*qs : 0.f;
            q[((size_t)(n*FF + f)*HPAD + h)*DD + d] = (bf16_t)v;
        }
    }
}

__device__ __forceinline__ float fast_tanh(float x) {
    const float t = __expf(2.f * x);
    return (t - 1.f) / (t + 1.f);
}

// ---------------- fused flash pass (MFMA), 32 h-rows/wave, 8 waves/block ----------
// grid (4, NF) x 512 threads: same 4 blocks/head as before -> FETCH unchanged,
// waves double vs the 64-row form: 4096 waves = 4 waves/SIMD target.
// __launch_bounds__(512, 2): R6's (512,4) forced VGPR=64 -> spills (FETCH 316 MB,
// WRITE 477 MB, MfmaUtil 3.7%). arg=2 caps at >=128 VGPR; state needs ~112.
// Vt double-buffered, 1 barrier/tile; staged by waves 0-3 only (validated map).
// Sᵀ = Q2·Q1ᵀ : C/D col=lane&31 -> h on lanes; row=(reg&3)+8*(reg>>2)+4*(lane>>5) -> g.
template<int MODE>
__global__ __launch_bounds__(512, 2) void flash(
    const bf16_t* __restrict__ q1, const bf16_t* __restrict__ q2,
    const bf16_t* __restrict__ vsrc, bf16_t* __restrict__ p1out,
    float* __restrict__ out)
{
    __shared__ __align__(16) bf16_t Vt[2][64*64];  // V^T tiles [d][p(g)], swizzled

    const int head = blockIdx.y;
    const int n = head >> 5, f = head & 31;
    const int tid = threadIdx.x;
    const int w = tid >> 6;                        // 0..7
    const int lane = tid & 63;
    const int lid = lane & 31;
    const int half = lane >> 5;
    const int hb = blockIdx.x * 256 + w * 32;      // 32 h-rows per wave

    const size_t qoff = (size_t)head * HPAD * DD;
    const int vswz = (lid & 7) ^ (lid >> 2);

    // Vt staging map (threads 0..255 only): rows g=4gq..4gq+3, cols 4dq..4dq+3
    const bool stg = (tid < 256);
    const int gq = (tid & 255) >> 4;
    const int dq = tid & 15;
    const int cgb = 4*((gq>>1)&1) + 8*(gq&1) + 16*(gq>>2);   // permuted col base

    const bf16_t* vptr = (MODE == 1) ? vsrc : q2;

    // hoisted per-thread base pointers
    const bf16_t* bp = q1 + qoff + (size_t)(hb + lid)*DD + 8*half;
    const bf16_t* ap = q2 + qoff + (size_t)lid*DD + 8*half;
    const bf16_t* vp = vptr + qoff + (size_t)(4*gq)*DD + 4*dq;

    // Q1 B-fragments, persistent in registers (pre-scaled by QSCALE in conv)
    bf16x8 bq1[4];
#pragma unroll
    for (int kt = 0; kt < 4; ++kt)
        bq1[kt] = *(const bf16x8*)&bp[16*kt];

    // A-fragments for tile 0 (from global)
    bf16x8 aq[2][4];
#pragma unroll
    for (int mt = 0; mt < 2; ++mt)
#pragma unroll
        for (int kt = 0; kt < 4; ++kt)
            aq[mt][kt] = *(const bf16x8*)&ap[(size_t)(32*mt)*DD + 16*kt];

    // V staging regs: tile 0 -> write buffer 0 now; then prefetch tile 1
    bf16x4 rV[4];
    if (stg) {
#pragma unroll
        for (int i = 0; i < 4; ++i)
            rV[i] = *(const bf16x4*)&vp[(size_t)i*DD];
#pragma unroll
        for (int j = 0; j < 4; ++j) {
            bf16x4 c = { rV[0][j], rV[1][j], rV[2][j], rV[3][j] };
            *(bf16x4*)&Vt[0][vaddr(4*dq + j, cgb)] = c;
        }
#pragma unroll
        for (int i = 0; i < 4; ++i)
            rV[i] = *(const bf16x4*)&vp[(size_t)(64 + i)*DD];
    }

    f32x16 O[2] = {};
    float lacc = 0.f;

    __syncthreads();                               // Vt[0] ready

    for (int t = 0; t < 16; ++t) {
        const int g0 = t << 6;
        const bf16_t* vtc = Vt[t & 1];
        const bool tail = (t == 15);

        // stage NEXT V tile into the inactive buffer (rV holds tile t+1 data),
        // then prefetch rV for tile t+2 -- overlapped with this tile's compute
        if (stg && t + 1 < 16) {
            bf16_t* vtn = Vt[(t + 1) & 1];
#pragma unroll
            for (int j = 0; j < 4; ++j) {
                bf16x4 c = { rV[0][j], rV[1][j], rV[2][j], rV[3][j] };
                *(bf16x4*)&vtn[vaddr(4*dq + j, cgb)] = c;
            }
            if (t + 2 < 16) {
#pragma unroll
                for (int i = 0; i < 4; ++i)
                    rV[i] = *(const bf16x4*)&vp[(size_t)((t + 2)*64 + i)*DD];
            }
        }

#pragma unroll
        for (int mt = 0; mt < 2; ++mt) {
            // ---- S-phase: A-frags from registers (global-prefetched) ----
            f32x16 C = {};
            __builtin_amdgcn_s_setprio(1);
#pragma unroll
            for (int kt = 0; kt < 4; ++kt)
                C = __builtin_amdgcn_mfma_f32_32x32x16_bf16(aq[mt][kt], bq1[kt], C, 0,0,0);
            __builtin_amdgcn_s_setprio(0);
            // reload this mt's A-frags for the NEXT tile (long latency window)
            if (t + 1 < 16) {
#pragma unroll
                for (int kt = 0; kt < 4; ++kt)
                    aq[mt][kt] = *(const bf16x8*)&ap[(size_t)((t + 1)*64 + 32*mt)*DD + 16*kt];
            }
            // ---- exp + pack PV A-frags (no mul: q1 pre-scaled) ----
            bf16x8 af[2];
            float ls = 0.f;
#pragma unroll
            for (int s = 0; s < 16; ++s) {
                float e = EXP2(C[s]);
                if (tail) {
                    const int gg = g0 + 32*mt + (s&3) + 8*(s>>2) + 4*half;
                    if (gg >= HP) e = 0.f;
                }
                ls += e;
                af[s>>3][s&7] = (bf16_t)e;
            }
            lacc += ls;
            // ---- PV: swizzled Vt b128 reads (conflict-free, validated R4) ----
            __builtin_amdgcn_s_setprio(1);
#pragma unroll
            for (int u = 0; u < 2; ++u) {
#pragma unroll
                for (int dt = 0; dt < 2; ++dt) {
                    const int chunk = (4*mt + 2*u + half) ^ vswz;
                    bf16x8 b = *(const bf16x8*)&vtc[(32*dt + lid)*64 + chunk*8];
                    O[dt] = __builtin_amdgcn_mfma_f32_32x32x16_bf16(af[u], b, O[dt], 0,0,0);
                }
            }
            __builtin_amdgcn_s_setprio(0);
        }
        __syncthreads();                           // vtn writes visible; vtc free
    }

    // ---- epilogue ----
    const float l = lacc + __shfl_xor(lacc, 32);
    const float linv = 1.f / l;
#pragma unroll
    for (int s = 0; s < 16; ++s) {
        const int R = (s&3) + 8*(s>>2) + 4*half;
        const float li = __shfl(linv, R);
        const int hg = hb + R;
#pragma unroll
        for (int dt = 0; dt < 2; ++dt) {
            const int d = 32*dt + lid;
            const float val = O[dt][s] * li;
            if (hg < HP)
                out[(((size_t)n*HP + hg)*FF + f)*DD + d] = fast_tanh(val);
            if (MODE == 0)   // zero-pad p1 rows >= HP so pass B stages clean data
                p1out[qoff + (size_t)hg*DD + d] = (bf16_t)(hg < HP ? val : 0.f);
        }
    }
}

extern "C" void kernel_launch(void* const* d_in, const int* in_sizes, int n_in,
                              void* d_out, int out_size, void* d_ws, size_t ws_size,
                              hipStream_t stream)
{
    const float* prot1 = (const float*)d_in[0];
    const float* prot2 = (const float*)d_in[1];
    const float* Wt    = (const float*)d_in[2];
    float* out = (float*)d_out;

    bf16_t* q1b = (bf16_t*)d_ws;
    bf16_t* q2b = q1b + QWS;
    bf16_t* p1b = q2b + QWS;
    float* Wp   = (float*)(p1b + QWS);

    wprep_kernel<<<dim3(448), 256, 0, stream>>>(Wt, Wp);
    conv_kernel<<<dim3(64, 4, 8), 256, 0, stream>>>(prot1, prot2, Wp, q1b, q2b);
    flash<0><<<dim3(4, NF), 512, 0, stream>>>(q1b, q2b, q2b, p1b, out);
    flash<1><<<dim3(4, NF), 512, 0, stream>>>(q1b, q2b, p1b, p1b, out + QOUT);
}

// Round 8
// 263.551 us; speedup vs baseline: 3.0752x; 2.7334x over previous
//
#include <hip/hip_runtime.h>
#include <math.h>

typedef __bf16 bf16_t;
typedef bf16_t bf16x4 __attribute__((ext_vector_type(4)));
typedef bf16_t bf16x8 __attribute__((ext_vector_type(8)));
typedef float  f32x16 __attribute__((ext_vector_type(16)));

#define HH 1024
#define CC 8
#define DD 64
#define FF 32
#define WW 7
#define HP 1018
#define HPAD 1024
#define NF 128
#define QOUT (NF*HP*DD)
#define QWS ((size_t)NF*HPAD*DD)

#if __has_builtin(__builtin_amdgcn_exp2f)
#define EXP2(x) __builtin_amdgcn_exp2f(x)
#else
#define EXP2(x) __expf((x) * 0.6931471805599453f)
#endif

// q1 is pre-scaled by log2(e)/1018 at conv time, so flash computes exp2(S) directly.
#define QSCALE (1.442695040888963f / 1018.f)

// Vt: row stride 64 bf16, XOR-swizzled 8-element chunks (validated R4):
//   addr(row, col) = row*64 + (((col>>3) ^ (row&7) ^ ((row>>2)&7))<<3) + (col&7)
__device__ __forceinline__ int vaddr(int row, int col) {
    return row*64 + ((((col>>3) ^ (row&7) ^ ((row>>2)&7)))<<3) + (col&7);
}

// ---------------- W transpose: Wt[f][c][d][j] -> Wp[f][c][j][d] ----------------
__global__ __launch_bounds__(256) void wprep_kernel(
    const float* __restrict__ Wt, float* __restrict__ Wp)
{
    const int idx = blockIdx.x * 256 + threadIdx.x;
    if (idx < FF*CC*DD*WW) {
        const int j = idx % WW;
        int t = idx / WW;
        const int d = t % DD; t /= DD;
        const int c = t % CC;
        const int f = t / CC;
        Wp[((f*CC + c)*WW + j)*DD + d] = Wt[idx];
    }
}

// ---------------- projection (grouped conv) ----------------
// 16-row h-tiles: staged window 22 rows = 45 KB LDS -> 3 blocks/CU.
// xs identity copy [row][c][d]; compute reads xs[row*512 + c*64 + d]: lanes differ
// only in d -> 2 lanes/bank, conflict-free.
// grid (64, 4, 8): z&1 selects input, z>>1 selects filter pair (2 f/thread).
__global__ __launch_bounds__(256, 3) void conv_kernel(
    const float* __restrict__ x1, const float* __restrict__ x2,
    const float* __restrict__ Wp, bf16_t* __restrict__ q1, bf16_t* __restrict__ q2)
{
    __shared__ float xs[22*512];
    const int zin = blockIdx.z & 1;
    const int fh = blockIdx.z >> 1;       // 0..3
    const float* x = zin ? x2 : x1;
    bf16_t* q = zin ? q2 : q1;
    const float qs = zin ? 1.f : QSCALE;  // bake softmax scale into q1
    const int n = blockIdx.y;
    const int hb = blockIdx.x * 16;
    const int tid = threadIdx.x;

    const float4* xg = (const float4*)(x + (size_t)n*HH*512);
    float4* xsv = (float4*)xs;
#pragma unroll
    for (int it = 0; it < 11; ++it) {     // 22*128 / 256 = 11
        const int i = it*256 + tid;
        const int row = hb + (i >> 7);
        float4 v = {0.f, 0.f, 0.f, 0.f};
        if (row < HH) v = xg[(size_t)row*128 + (i & 127)];
        xsv[i] = v;
    }

    const int d = tid & 63;
    const int fq = tid >> 6;

    // weights for this thread's 2 filters, issued before the barrier
    float w[2][CC][WW];
#pragma unroll
    for (int fi = 0; fi < 2; ++fi) {
        const int f = fq*8 + fh*2 + fi;
#pragma unroll
        for (int c = 0; c < CC; ++c)
#pragma unroll
            for (int j = 0; j < WW; ++j)
                w[fi][c][j] = Wp[((f*CC + c)*WW + j)*DD + d];
    }

    __syncthreads();

    float acc[2][16];
#pragma unroll
    for (int fi = 0; fi < 2; ++fi)
#pragma unroll
        for (int i = 0; i < 16; ++i) acc[fi][i] = 0.f;

#pragma unroll
    for (int rr = 0; rr < 22; ++rr) {
        float xv[CC];
#pragma unroll
        for (int c = 0; c < CC; ++c)
            xv[c] = xs[rr*512 + c*64 + d];
#pragma unroll
        for (int fi = 0; fi < 2; ++fi)
#pragma unroll
            for (int j = 0; j < WW; ++j) {
                const int i = rr - j;          // compile-time guard (full unroll)
                if (i >= 0 && i < 16) {
#pragma unroll
                    for (int c = 0; c < CC; ++c)
                        acc[fi][i] = fmaf(xv[c], w[fi][c][j], acc[fi][i]);
                }
            }
    }

#pragma unroll
    for (int fi = 0; fi < 2; ++fi) {
        const int f = fq*8 + fh*2 + fi;
#pragma unroll
        for (int i = 0; i < 16; ++i) {
            const int h = hb + i;
            const float v = (h < HP) ? acc[fi][i]*qs : 0.f;
            q[((size_t)(n*FF + f)*HPAD + h)*DD + d] = (bf16_t)v;
        }
    }
}

__device__ __forceinline__ float fast_tanh(float x) {
    const float t = __expf(2.f * x);
    return (t - 1.f) / (t + 1.f);
}

// ---------------- fused flash pass (MFMA), 32 h-rows/wave, 8 waves/block ----------
// grid (4, NF) x 512 threads: same 4 blocks/head -> no stream duplication.
// Target: 2 blocks/CU = 16 waves/CU = 4 waves/SIMD under the 128-VGPR cap.
// LEAN STATE (R7 spilled at cap 128 with aq[2][4] full-tile prefetch):
//   single aq[4] (16 VGPR), reloaded after each S-phase for the NEXT half-tile
//   (~600-cy window; TLP from 4 waves/SIMD covers the rest).
//   state: bq1 16 + aq 16 + O 32 + rV 8 + C 16 + af 8 + addr ~12 = ~108 < 128.
// Vt double-buffered, 1 barrier/tile; staged by waves 0-3 only (validated map).
// Sᵀ = Q2·Q1ᵀ : C/D col=lane&31 -> h on lanes; row=(reg&3)+8*(reg>>2)+4*(lane>>5) -> g.
template<int MODE>
__global__ __launch_bounds__(512, 2) void flash(
    const bf16_t* __restrict__ q1, const bf16_t* __restrict__ q2,
    const bf16_t* __restrict__ vsrc, bf16_t* __restrict__ p1out,
    float* __restrict__ out)
{
    __shared__ __align__(16) bf16_t Vt[2][64*64];  // V^T tiles [d][p(g)], swizzled

    const int head = blockIdx.y;
    const int n = head >> 5, f = head & 31;
    const int tid = threadIdx.x;
    const int w = tid >> 6;                        // 0..7
    const int lane = tid & 63;
    const int lid = lane & 31;
    const int half = lane >> 5;
    const int hb = blockIdx.x * 256 + w * 32;      // 32 h-rows per wave

    const size_t qoff = (size_t)head * HPAD * DD;
    const int vswz = (lid & 7) ^ (lid >> 2);

    // Vt staging map (threads 0..255 only): rows g=4gq..4gq+3, cols 4dq..4dq+3
    const bool stg = (tid < 256);
    const int gq = (tid & 255) >> 4;
    const int dq = tid & 15;
    const int cgb = 4*((gq>>1)&1) + 8*(gq&1) + 16*(gq>>2);   // permuted col base

    const bf16_t* vptr = (MODE == 1) ? vsrc : q2;

    // hoisted per-thread base pointers
    const bf16_t* bp = q1 + qoff + (size_t)(hb + lid)*DD + 8*half;
    const bf16_t* ap = q2 + qoff + (size_t)lid*DD + 8*half;
    const bf16_t* vp = vptr + qoff + (size_t)(4*gq)*DD + 4*dq;

    // Q1 B-fragments, persistent in registers (pre-scaled by QSCALE in conv)
    bf16x8 bq1[4];
#pragma unroll
    for (int kt = 0; kt < 4; ++kt)
        bq1[kt] = *(const bf16x8*)&bp[16*kt];

    // Single A-fragment set: holds the NEXT half-tile to be consumed.
    bf16x8 aq[4];
#pragma unroll
    for (int kt = 0; kt < 4; ++kt)
        aq[kt] = *(const bf16x8*)&ap[16*kt];       // (t=0, mt=0)

    // V staging regs: tile 0 -> write buffer 0 now; then prefetch tile 1
    bf16x4 rV[4];
    if (stg) {
#pragma unroll
        for (int i = 0; i < 4; ++i)
            rV[i] = *(const bf16x4*)&vp[(size_t)i*DD];
#pragma unroll
        for (int j = 0; j < 4; ++j) {
            bf16x4 c = { rV[0][j], rV[1][j], rV[2][j], rV[3][j] };
            *(bf16x4*)&Vt[0][vaddr(4*dq + j, cgb)] = c;
        }
#pragma unroll
        for (int i = 0; i < 4; ++i)
            rV[i] = *(const bf16x4*)&vp[(size_t)(64 + i)*DD];
    }

    f32x16 O[2] = {};
    float lacc = 0.f;

    __syncthreads();                               // Vt[0] ready

    for (int t = 0; t < 16; ++t) {
        const int g0 = t << 6;
        const bf16_t* vtc = Vt[t & 1];
        const bool tail = (t == 15);

        // stage NEXT V tile into the inactive buffer (rV holds tile t+1 data),
        // then prefetch rV for tile t+2 -- overlapped with this tile's compute
        if (stg && t + 1 < 16) {
            bf16_t* vtn = Vt[(t + 1) & 1];
#pragma unroll
            for (int j = 0; j < 4; ++j) {
                bf16x4 c = { rV[0][j], rV[1][j], rV[2][j], rV[3][j] };
                *(bf16x4*)&vtn[vaddr(4*dq + j, cgb)] = c;
            }
            if (t + 2 < 16) {
#pragma unroll
                for (int i = 0; i < 4; ++i)
                    rV[i] = *(const bf16x4*)&vp[(size_t)((t + 2)*64 + i)*DD];
            }
        }

#pragma unroll
        for (int mt = 0; mt < 2; ++mt) {
            // ---- S-phase: A-frags from registers (prefetched last half-tile) ----
            f32x16 C = {};
            __builtin_amdgcn_s_setprio(1);
#pragma unroll
            for (int kt = 0; kt < 4; ++kt)
                C = __builtin_amdgcn_mfma_f32_32x32x16_bf16(aq[kt], bq1[kt], C, 0,0,0);
            __builtin_amdgcn_s_setprio(0);
            // reload aq for the NEXT half-tile (in flight during exp+PV, ~600 cy)
            if (mt == 0) {
#pragma unroll
                for (int kt = 0; kt < 4; ++kt)
                    aq[kt] = *(const bf16x8*)&ap[(size_t)(g0 + 32)*DD + 16*kt];
            } else if (t + 1 < 16) {
#pragma unroll
                for (int kt = 0; kt < 4; ++kt)
                    aq[kt] = *(const bf16x8*)&ap[(size_t)(g0 + 64)*DD + 16*kt];
            }
            // ---- exp + pack PV A-frags (no mul: q1 pre-scaled) ----
            bf16x8 af[2];
            float ls = 0.f;
#pragma unroll
            for (int s = 0; s < 16; ++s) {
                float e = EXP2(C[s]);
                if (tail) {
                    const int gg = g0 + 32*mt + (s&3) + 8*(s>>2) + 4*half;
                    if (gg >= HP) e = 0.f;
                }
                ls += e;
                af[s>>3][s&7] = (bf16_t)e;
            }
            lacc += ls;
            // ---- PV: swizzled Vt b128 reads (conflict-free, validated R4) ----
            __builtin_amdgcn_s_setprio(1);
#pragma unroll
            for (int u = 0; u < 2; ++u) {
#pragma unroll
                for (int dt = 0; dt < 2; ++dt) {
                    const int chunk = (4*mt + 2*u + half) ^ vswz;
                    bf16x8 b = *(const bf16x8*)&vtc[(32*dt + lid)*64 + chunk*8];
                    O[dt] = __builtin_amdgcn_mfma_f32_32x32x16_bf16(af[u], b, O[dt], 0,0,0);
                }
            }
            __builtin_amdgcn_s_setprio(0);
        }
        __syncthreads();                           // vtn writes visible; vtc free
    }

    // ---- epilogue ----
    const float l = lacc + __shfl_xor(lacc, 32);
    const float linv = 1.f / l;
#pragma unroll
    for (int s = 0; s < 16; ++s) {
        const int R = (s&3) + 8*(s>>2) + 4*half;
        const float li = __shfl(linv, R);
        const int hg = hb + R;
#pragma unroll
        for (int dt = 0; dt < 2; ++dt) {
            const int d = 32*dt + lid;
            const float val = O[dt][s] * li;
            if (hg < HP)
                out[(((size_t)n*HP + hg)*FF + f)*DD + d] = fast_tanh(val);
            if (MODE == 0)   // zero-pad p1 rows >= HP so pass B stages clean data
                p1out[qoff + (size_t)hg*DD + d] = (bf16_t)(hg < HP ? val : 0.f);
        }
    }
}

extern "C" void kernel_launch(void* const* d_in, const int* in_sizes, int n_in,
                              void* d_out, int out_size, void* d_ws, size_t ws_size,
                              hipStream_t stream)
{
    const float* prot1 = (const float*)d_in[0];
    const float* prot2 = (const float*)d_in[1];
    const float* Wt    = (const float*)d_in[2];
    float* out = (float*)d_out;

    bf16_t* q1b = (bf16_t*)d_ws;
    bf16_t* q2b = q1b + QWS;
    bf16_t* p1b = q2b + QWS;
    float* Wp   = (float*)(p1b + QWS);

    wprep_kernel<<<dim3(448), 256, 0, stream>>>(Wt, Wp);
    conv_kernel<<<dim3(64, 4, 8), 256, 0, stream>>>(prot1, prot2, Wp, q1b, q2b);
    flash<0><<<dim3(4, NF), 512, 0, stream>>>(q1b, q2b, q2b, p1b, out);
    flash<1><<<dim3(4, NF), 512, 0, stream>>>(q1b, q2b, p1b, p1b, out + QOUT);
}

// Round 9
// 208.614 us; speedup vs baseline: 3.8850x; 1.2633x over previous
//
#include <hip/hip_runtime.h>
#include <math.h>

typedef __bf16 bf16_t;
typedef bf16_t bf16x4 __attribute__((ext_vector_type(4)));
typedef bf16_t bf16x8 __attribute__((ext_vector_type(8)));
typedef float  f32x16 __attribute__((ext_vector_type(16)));

#define HH 1024
#define CC 8
#define DD 64
#define FF 32
#define WW 7
#define HP 1018
#define HPAD 1024
#define NF 128
#define QOUT (NF*HP*DD)
#define QWS ((size_t)NF*HPAD*DD)

#if __has_builtin(__builtin_amdgcn_exp2f)
#define EXP2(x) __builtin_amdgcn_exp2f(x)
#else
#define EXP2(x) __expf((x) * 0.6931471805599453f)
#endif

// q1 is pre-scaled by log2(e)/1018 at conv time, so flash computes exp2(S) directly.
#define QSCALE (1.442695040888963f / 1018.f)

// Vt: row stride 64 bf16, XOR-swizzled 8-element chunks (validated R4):
//   addr(row, col) = row*64 + (((col>>3) ^ (row&7) ^ ((row>>2)&7))<<3) + (col&7)
__device__ __forceinline__ int vaddr(int row, int col) {
    return row*64 + ((((col>>3) ^ (row&7) ^ ((row>>2)&7)))<<3) + (col&7);
}

// ---------------- W transpose: Wt[f][c][d][j] -> Wp[f][c][j][d] ----------------
__global__ __launch_bounds__(256) void wprep_kernel(
    const float* __restrict__ Wt, float* __restrict__ Wp)
{
    const int idx = blockIdx.x * 256 + threadIdx.x;
    if (idx < FF*CC*DD*WW) {
        const int j = idx % WW;
        int t = idx / WW;
        const int d = t % DD; t /= DD;
        const int c = t % CC;
        const int f = t / CC;
        Wp[((f*CC + c)*WW + j)*DD + d] = Wt[idx];
    }
}

// ---------------- projection (grouped conv) ----------------
// 16-row h-tiles: staged window 22 rows = 45 KB LDS -> 3 blocks/CU.
// xs identity copy [row][c][d]; compute reads xs[row*512 + c*64 + d]: lanes differ
// only in d -> 2 lanes/bank, conflict-free.
// grid (64, 4, 8): z&1 selects input, z>>1 selects filter pair (2 f/thread).
// (This exact conv benched as part of the 207.9 us best config.)
__global__ __launch_bounds__(256, 3) void conv_kernel(
    const float* __restrict__ x1, const float* __restrict__ x2,
    const float* __restrict__ Wp, bf16_t* __restrict__ q1, bf16_t* __restrict__ q2)
{
    __shared__ float xs[22*512];
    const int zin = blockIdx.z & 1;
    const int fh = blockIdx.z >> 1;       // 0..3
    const float* x = zin ? x2 : x1;
    bf16_t* q = zin ? q2 : q1;
    const float qs = zin ? 1.f : QSCALE;  // bake softmax scale into q1
    const int n = blockIdx.y;
    const int hb = blockIdx.x * 16;
    const int tid = threadIdx.x;

    const float4* xg = (const float4*)(x + (size_t)n*HH*512);
    float4* xsv = (float4*)xs;
#pragma unroll
    for (int it = 0; it < 11; ++it) {     // 22*128 / 256 = 11
        const int i = it*256 + tid;
        const int row = hb + (i >> 7);
        float4 v = {0.f, 0.f, 0.f, 0.f};
        if (row < HH) v = xg[(size_t)row*128 + (i & 127)];
        xsv[i] = v;
    }

    const int d = tid & 63;
    const int fq = tid >> 6;

    // weights for this thread's 2 filters, issued before the barrier
    float w[2][CC][WW];
#pragma unroll
    for (int fi = 0; fi < 2; ++fi) {
        const int f = fq*8 + fh*2 + fi;
#pragma unroll
        for (int c = 0; c < CC; ++c)
#pragma unroll
            for (int j = 0; j < WW; ++j)
                w[fi][c][j] = Wp[((f*CC + c)*WW + j)*DD + d];
    }

    __syncthreads();

    float acc[2][16];
#pragma unroll
    for (int fi = 0; fi < 2; ++fi)
#pragma unroll
        for (int i = 0; i < 16; ++i) acc[fi][i] = 0.f;

#pragma unroll
    for (int rr = 0; rr < 22; ++rr) {
        float xv[CC];
#pragma unroll
        for (int c = 0; c < CC; ++c)
            xv[c] = xs[rr*512 + c*64 + d];
#pragma unroll
        for (int fi = 0; fi < 2; ++fi)
#pragma unroll
            for (int j = 0; j < WW; ++j) {
                const int i = rr - j;          // compile-time guard (full unroll)
                if (i >= 0 && i < 16) {
#pragma unroll
                    for (int c = 0; c < CC; ++c)
                        acc[fi][i] = fmaf(xv[c], w[fi][c][j], acc[fi][i]);
                }
            }
    }

#pragma unroll
    for (int fi = 0; fi < 2; ++fi) {
        const int f = fq*8 + fh*2 + fi;
#pragma unroll
        for (int i = 0; i < 16; ++i) {
            const int h = hb + i;
            const float v = (h < HP) ? acc[fi][i]*qs : 0.f;
            q[((size_t)(n*FF + f)*HPAD + h)*DD + d] = (bf16_t)v;
        }
    }
}

__device__ __forceinline__ float fast_tanh(float x) {
    const float t = __expf(2.f * x);
    return (t - 1.f) / (t + 1.f);
}

// One half-tile step (mtv MUST be a literal 0/1): S -> aq reload -> exp -> PV.
#define MT_STEP(mtv) {                                                            \
    f32x16 C[2] = {};                                                             \
    __builtin_amdgcn_s_setprio(1);                                                \
    _Pragma("unroll")                                                             \
    for (int kt = 0; kt < 4; ++kt) {                                              \
        C[0] = __builtin_amdgcn_mfma_f32_32x32x16_bf16(aq[mtv][kt], bq1[0][kt], C[0], 0,0,0); \
        C[1] = __builtin_amdgcn_mfma_f32_32x32x16_bf16(aq[mtv][kt], bq1[1][kt], C[1], 0,0,0); \
    }                                                                             \
    __builtin_amdgcn_s_setprio(0);                                                \
    if (g0 + 64 < HPAD) {                                                         \
        _Pragma("unroll")                                                         \
        for (int kt = 0; kt < 4; ++kt)                                            \
            aq[mtv][kt] = *(const bf16x8*)&ap[(size_t)(g0 + 64 + 32*(mtv))*DD + 16*kt]; \
    }                                                                             \
    bf16x8 af[2][2];                                                              \
    _Pragma("unroll")                                                             \
    for (int nt = 0; nt < 2; ++nt) {                                              \
        float ls = 0.f;                                                           \
        _Pragma("unroll")                                                         \
        for (int s = 0; s < 16; ++s) {                                            \
            float e = EXP2(C[nt][s]);                                             \
            if (tail) {                                                           \
                const int gg = g0 + 32*(mtv) + (s&3) + 8*(s>>2) + 4*half;         \
                if (gg >= HP) e = 0.f;                                            \
            }                                                                     \
            ls += e;                                                              \
            af[nt][s>>3][s&7] = (bf16_t)e;                                        \
        }                                                                         \
        lacc[nt] += ls;                                                           \
    }                                                                             \
    __builtin_amdgcn_s_setprio(1);                                                \
    _Pragma("unroll")                                                             \
    for (int u = 0; u < 2; ++u) {                                                 \
        _Pragma("unroll")                                                         \
        for (int dt = 0; dt < 2; ++dt) {                                          \
            const int chunk = (4*(mtv) + 2*u + half) ^ vswz;                      \
            bf16x8 b = *(const bf16x8*)&vtc[(32*dt + lid)*64 + chunk*8];          \
            O[0][dt] = __builtin_amdgcn_mfma_f32_32x32x16_bf16(af[0][u], b, O[0][dt], 0,0,0); \
            O[1][dt] = __builtin_amdgcn_mfma_f32_32x32x16_bf16(af[1][u], b, O[1][dt], 0,0,0); \
        }                                                                         \
    }                                                                             \
    __builtin_amdgcn_s_setprio(0); }

// ---------------- fused flash pass (MFMA), 64 h-rows/wave ----------------
// grid (4, NF), 2 blocks/CU. Vt double-buffered, 1 barrier/tile (benched 57 us).
// NEW: wave-phase decorrelation. All resident waves used to execute S/exp/PV in
// lockstep (all in exp together -> trans-pipe pileup, MFMA idle; MfmaUtil 23% vs
// ~46% if interleaved). Odd-parity waves (w^bx^by) process the two mt half-tiles
// in OPPOSITE order: while parity-0 runs S(mt0) on the MFMA pipe, parity-1 runs
// exp of its first half-tile on the trans pipe. Pure commutative reorder.
template<int MODE>
__global__ __launch_bounds__(256, 2) void flash(
    const bf16_t* __restrict__ q1, const bf16_t* __restrict__ q2,
    const bf16_t* __restrict__ vsrc, bf16_t* __restrict__ p1out,
    float* __restrict__ out)
{
    __shared__ __align__(16) bf16_t Vt[2][64*64];  // V^T tiles [d][p(g)], swizzled

    const int head = blockIdx.y;
    const int n = head >> 5, f = head & 31;
    const int tid = threadIdx.x;
    const int w = tid >> 6;
    const int lane = tid & 63;
    const int lid = lane & 31;
    const int half = lane >> 5;
    const int hb = blockIdx.x * 256 + w * 64;
    const bool odd = ((w ^ blockIdx.x ^ blockIdx.y) & 1) != 0;

    const size_t qoff = (size_t)head * HPAD * DD;
    const int vswz = (lid & 7) ^ (lid >> 2);

    // Vt staging map: thread stages rows g=4gq..4gq+3, cols 4dq..4dq+3
    const int gq = tid >> 4;
    const int dq = tid & 15;
    const int cgb = 4*((gq>>1)&1) + 8*(gq&1) + 16*(gq>>2);   // permuted col base

    const bf16_t* vptr = (MODE == 1) ? vsrc : q2;

    // hoisted per-thread base pointers
    const bf16_t* bp = q1 + qoff + (size_t)(hb + lid)*DD + 8*half;
    const bf16_t* ap = q2 + qoff + (size_t)lid*DD + 8*half;
    const bf16_t* vp = vptr + qoff + (size_t)(4*gq)*DD + 4*dq;

    // Q1 B-fragments, persistent in registers (pre-scaled by QSCALE in conv)
    bf16x8 bq1[2][4];
#pragma unroll
    for (int nt = 0; nt < 2; ++nt)
#pragma unroll
        for (int kt = 0; kt < 4; ++kt)
            bq1[nt][kt] = *(const bf16x8*)&bp[(size_t)(32*nt)*DD + 16*kt];

    // A-fragments for tile 0 (from global)
    bf16x8 aq[2][4];
#pragma unroll
    for (int mt = 0; mt < 2; ++mt)
#pragma unroll
        for (int kt = 0; kt < 4; ++kt)
            aq[mt][kt] = *(const bf16x8*)&ap[(size_t)(32*mt)*DD + 16*kt];

    // V staging regs: tile 0 -> write buffer 0 now; then prefetch tile 1
    bf16x4 rV[4];
#pragma unroll
    for (int i = 0; i < 4; ++i)
        rV[i] = *(const bf16x4*)&vp[(size_t)i*DD];
#pragma unroll
    for (int j = 0; j < 4; ++j) {
        bf16x4 c = { rV[0][j], rV[1][j], rV[2][j], rV[3][j] };
        *(bf16x4*)&Vt[0][vaddr(4*dq + j, cgb)] = c;
    }
#pragma unroll
    for (int i = 0; i < 4; ++i)
        rV[i] = *(const bf16x4*)&vp[(size_t)(64 + i)*DD];

    f32x16 O[2][2] = {};
    float lacc[2] = {0.f, 0.f};

    __syncthreads();                               // Vt[0] ready

    for (int t = 0; t < 16; ++t) {
        const int g0 = t << 6;
        const bf16_t* vtc = Vt[t & 1];

        // stage NEXT tile into the inactive buffer (rV holds tile t+1 data),
        // then prefetch rV for tile t+2 -- overlapped with this tile's compute
        if (t + 1 < 16) {
            bf16_t* vtn = Vt[(t + 1) & 1];
#pragma unroll
            for (int j = 0; j < 4; ++j) {
                bf16x4 c = { rV[0][j], rV[1][j], rV[2][j], rV[3][j] };
                *(bf16x4*)&vtn[vaddr(4*dq + j, cgb)] = c;
            }
            if (t + 2 < 16) {
#pragma unroll
                for (int i = 0; i < 4; ++i)
                    rV[i] = *(const bf16x4*)&vp[(size_t)((t + 2)*64 + i)*DD];
            }
        }

        const bool tail = (g0 + 64 > HP);

        if (odd) { MT_STEP(1); MT_STEP(0); }
        else     { MT_STEP(0); MT_STEP(1); }

        __syncthreads();                           // vtn writes visible; vtc free
    }

    // ---- epilogue ----
    float linv[2];
#pragma unroll
    for (int nt = 0; nt < 2; ++nt) {
        const float l = lacc[nt] + __shfl_xor(lacc[nt], 32);
        linv[nt] = 1.f / l;
    }
#pragma unroll
    for (int ht = 0; ht < 2; ++ht) {
#pragma unroll
        for (int s = 0; s < 16; ++s) {
            const int R = (s&3) + 8*(s>>2) + 4*half;
            const float li = __shfl(linv[ht], R);
            const int hg = hb + 32*ht + R;
#pragma unroll
            for (int dt = 0; dt < 2; ++dt) {
                const int d = 32*dt + lid;
                const float val = O[ht][dt][s] * li;
                if (hg < HP)
                    out[(((size_t)n*HP + hg)*FF + f)*DD + d] = fast_tanh(val);
                if (MODE == 0)   // zero-pad p1 rows >= HP so pass B stages clean data
                    p1out[qoff + (size_t)hg*DD + d] = (bf16_t)(hg < HP ? val : 0.f);
            }
        }
    }
}

extern "C" void kernel_launch(void* const* d_in, const int* in_sizes, int n_in,
                              void* d_out, int out_size, void* d_ws, size_t ws_size,
                              hipStream_t stream)
{
    const float* prot1 = (const float*)d_in[0];
    const float* prot2 = (const float*)d_in[1];
    const float* Wt    = (const float*)d_in[2];
    float* out = (float*)d_out;

    bf16_t* q1b = (bf16_t*)d_ws;
    bf16_t* q2b = q1b + QWS;
    bf16_t* p1b = q2b + QWS;
    float* Wp   = (float*)(p1b + QWS);

    wprep_kernel<<<dim3(448), 256, 0, stream>>>(Wt, Wp);
    conv_kernel<<<dim3(64, 4, 8), 256, 0, stream>>>(prot1, prot2, Wp, q1b, q2b);
    flash<0><<<dim3(4, NF), 256, 0, stream>>>(q1b, q2b, q2b, p1b, out);
    flash<1><<<dim3(4, NF), 256, 0, stream>>>(q1b, q2b, p1b, p1b, out + QOUT);
}